// Round 2
// baseline (886.996 us; speedup 1.0000x reference)
//
#include <hip/hip_runtime.h>
#include <math.h>

#define T_TOKENS 32768
#define DIM 2048
#define N_EXPERTS 256
#define N_GROUPS 8
#define EPG 32            // experts per group
#define TOPK 8
#define TOPK_GROUPS 4
#define GROUP_TOPK 2
#define ROUTE_SCALE 2.5f

// ---------------------------------------------------------------------------
// Kernel 1: scores = sigmoid(X @ W^T)   X:(T,D) fp32, W:(E,D) fp32 -> S:(T,E)
// Classic 64x64 LDS-tiled fp32 GEMM, BK=16, 256 threads, 4x4 micro-tile.
// fp32 VALU-bound (no fp32 MFMA on CDNA4) — baseline; split-bf16 MFMA later.
// ---------------------------------------------------------------------------
__global__ __launch_bounds__(256) void gemm_sigmoid_kernel(
    const float* __restrict__ X, const float* __restrict__ W,
    float* __restrict__ S)
{
    // +4 pad: keeps rows 16B-aligned for float4 LDS reads, breaks pow2 stride
    __shared__ float Xs[16][68];
    __shared__ float Ws[16][68];

    const int m0 = blockIdx.y << 6;   // token tile origin
    const int n0 = blockIdx.x << 6;   // expert tile origin
    const int tid = threadIdx.x;
    const int tx = tid & 15;          // expert dir, 0..15
    const int ty = tid >> 4;          // token dir, 0..15
    const int lm = tid >> 2;          // load row 0..63
    const int lk = (tid & 3) << 2;    // load k offset {0,4,8,12}

    const float* xp = X + (size_t)(m0 + lm) * DIM + lk;
    const float* wp = W + (size_t)(n0 + lm) * DIM + lk;

    float acc[4][4];
    #pragma unroll
    for (int i = 0; i < 4; i++)
        #pragma unroll
        for (int j = 0; j < 4; j++) acc[i][j] = 0.f;

    for (int k0 = 0; k0 < DIM; k0 += 16) {
        float4 xa = *(const float4*)(xp + k0);
        float4 wa = *(const float4*)(wp + k0);
        __syncthreads();   // previous iter's LDS reads done
        // transposed store: Xs[k][m]
        Xs[lk + 0][lm] = xa.x; Xs[lk + 1][lm] = xa.y;
        Xs[lk + 2][lm] = xa.z; Xs[lk + 3][lm] = xa.w;
        Ws[lk + 0][lm] = wa.x; Ws[lk + 1][lm] = wa.y;
        Ws[lk + 2][lm] = wa.z; Ws[lk + 3][lm] = wa.w;
        __syncthreads();
        #pragma unroll
        for (int kk = 0; kk < 16; kk++) {
            float4 a = *(const float4*)&Xs[kk][ty << 2];  // broadcast across tx
            float4 b = *(const float4*)&Ws[kk][tx << 2];  // 64 consecutive floats
            acc[0][0] += a.x * b.x; acc[0][1] += a.x * b.y;
            acc[0][2] += a.x * b.z; acc[0][3] += a.x * b.w;
            acc[1][0] += a.y * b.x; acc[1][1] += a.y * b.y;
            acc[1][2] += a.y * b.z; acc[1][3] += a.y * b.w;
            acc[2][0] += a.z * b.x; acc[2][1] += a.z * b.y;
            acc[2][2] += a.z * b.z; acc[2][3] += a.z * b.w;
            acc[3][0] += a.w * b.x; acc[3][1] += a.w * b.y;
            acc[3][2] += a.w * b.z; acc[3][3] += a.w * b.w;
        }
    }

    #pragma unroll
    for (int i = 0; i < 4; i++) {
        const size_t row = (size_t)(m0 + (ty << 2) + i);
        #pragma unroll
        for (int j = 0; j < 4; j++) {
            const int col = n0 + (tx << 2) + j;
            S[row * N_EXPERTS + col] = 1.0f / (1.0f + expf(-acc[i][j]));
        }
    }
}

// ---------------------------------------------------------------------------
// Kernel 2: group-limited top-k routing. One thread per token.
// Replicates jax.lax.top_k tie-breaking exactly: descending value, ties ->
// lower index first (streaming insertion with strict > preserves this).
// NOTE: d_out is read back by the harness as float32 for BOTH outputs —
// indices must be written as float values, not int32 bit patterns.
// ---------------------------------------------------------------------------
__global__ __launch_bounds__(256) void route_kernel(
    const float* __restrict__ S, const float* __restrict__ bias,
    float* __restrict__ out_w, float* __restrict__ out_i)
{
    __shared__ float bsh[N_EXPERTS];
    bsh[threadIdx.x] = bias[threadIdx.x];
    __syncthreads();

    const int t = blockIdx.x * 256 + threadIdx.x;
    if (t >= T_TOKENS) return;
    const float* s = S + (size_t)t * N_EXPERTS;

    // --- per-group score = sum of top-2 biased values ---
    float gs[N_GROUPS];
    #pragma unroll
    for (int g = 0; g < N_GROUPS; g++) {
        float m1 = -INFINITY, m2 = -INFINITY;
        for (int j = 0; j < EPG; j++) {
            const float v = s[g * EPG + j] + bsh[g * EPG + j];
            if (v > m1) { m2 = m1; m1 = v; }
            else if (v > m2) { m2 = v; }
        }
        gs[g] = m1 + m2;
    }

    // --- keep mask: rank each group by (value desc, index asc), keep rank<4 ---
    unsigned keep = 0;
    #pragma unroll
    for (int g = 0; g < N_GROUPS; g++) {
        int cnt = 0;
        #pragma unroll
        for (int h = 0; h < N_GROUPS; h++)
            if (gs[h] > gs[g] || (gs[h] == gs[g] && h < g)) cnt++;
        if (cnt < TOPK_GROUPS) keep |= (1u << g);
    }

    // --- top-8 over kept experts (128 candidates), insertion sort of 8 ---
    float tv[TOPK]; int ti[TOPK];
    #pragma unroll
    for (int i = 0; i < TOPK; i++) { tv[i] = -INFINITY; ti[i] = 0; }
    for (int g = 0; g < N_GROUPS; g++) {
        if (!(keep & (1u << g))) continue;
        for (int j = 0; j < EPG; j++) {
            const int e = g * EPG + j;
            const float v = s[e] + bsh[e];
            if (v > tv[TOPK - 1]) {
                int pos = TOPK - 1;
                while (pos > 0 && v > tv[pos - 1]) {
                    tv[pos] = tv[pos - 1]; ti[pos] = ti[pos - 1]; pos--;
                }
                tv[pos] = v; ti[pos] = e;
            }
        }
    }

    // --- weights from RAW sigmoid scores at chosen indices ---
    float w[TOPK]; float sum = 0.f;
    #pragma unroll
    for (int i = 0; i < TOPK; i++) { w[i] = s[ti[i]]; sum += w[i]; }
    const float scale = ROUTE_SCALE / fmaxf(sum, 1e-10f);
    #pragma unroll
    for (int i = 0; i < TOPK; i++) {
        out_w[(size_t)t * TOPK + i] = w[i] * scale;
        out_i[(size_t)t * TOPK + i] = (float)ti[i];   // float-encoded indices
    }
}

extern "C" void kernel_launch(void* const* d_in, const int* in_sizes, int n_in,
                              void* d_out, int out_size, void* d_ws, size_t ws_size,
                              hipStream_t stream)
{
    const float* x = (const float*)d_in[0];     // (T, D)
    const float* w = (const float*)d_in[1];     // (E, D)
    const float* b = (const float*)d_in[2];     // (E,)

    float* scores = (float*)d_ws;               // (T, E) = 33.5 MB scratch
    float* out_w = (float*)d_out;                               // (T, 8) fp32
    float* out_i = (float*)d_out + (size_t)T_TOKENS * TOPK;     // (T, 8) as fp32

    dim3 grid(N_EXPERTS / 64, T_TOKENS / 64);   // 4 x 512 = 2048 blocks
    gemm_sigmoid_kernel<<<grid, 256, 0, stream>>>(x, w, scores);

    route_kernel<<<T_TOKENS / 256, 256, 0, stream>>>(scores, b, out_w, out_i);
}

// Round 4
// 749.826 us; speedup vs baseline: 1.1829x; 1.1829x over previous
//
#include <hip/hip_runtime.h>
#include <math.h>

#define T_TOKENS 32768
#define DIM 2048
#define N_EXPERTS 256
#define N_GROUPS 8
#define EPG 32
#define TOPK 8
#define TOPK_GROUPS 4
#define ROUTE_SCALE 2.5f

#define BM 128          // tokens per block
#define BK 32           // K-tile
#define KP 40           // padded LDS row (fp16 elems): 80B row -> conflict-free b128
#define KITERS (DIM / BK)
#define W_SCALE 256.0f  // pre-scale W so w_lo stays normal in fp16
#define INV_W_SCALE (1.0f / 256.0f)

typedef unsigned short u16;
typedef _Float16 f16x8 __attribute__((ext_vector_type(8)));
typedef float f32x4 __attribute__((ext_vector_type(4)));

__device__ __forceinline__ u16 f16_bits(_Float16 h) {
    union { _Float16 f; u16 u; } c; c.f = h; return c.u;
}

// ---------------------------------------------------------------------------
// Kernel 1: split 256*W (fp32) into fp16 hi/lo planes. 2 MB, L2-resident.
// fp16 pair captures 22+ mantissa bits; x*w' products are exact in fp32.
// ---------------------------------------------------------------------------
__global__ __launch_bounds__(256) void convert_w(
    const float* __restrict__ W, u16* __restrict__ Whi, u16* __restrict__ Wlo)
{
    const int i = blockIdx.x * 256 + threadIdx.x;   // 524288 total
    const float x = W[i] * W_SCALE;
    const _Float16 hi = (_Float16)x;
    const _Float16 lo = (_Float16)(x - (float)hi);
    Whi[i] = f16_bits(hi);
    Wlo[i] = f16_bits(lo);
}

// ---------------------------------------------------------------------------
// Kernel 2: fused  sigmoid(X @ W^T) + bias  ->  group-limited top-k routing.
// Block: 512 thr (8 waves, wave grid 2m x 4n), tile 128 tokens x 256 experts.
// Split-fp16 3-term MFMA (hh + hl + lh): logit error ~1e-7, fp32 class.
// Scores live only in LDS (64KB union with staging); routing fused in epilogue.
// ---------------------------------------------------------------------------
__global__ __launch_bounds__(512, 2) void fused_gate(
    const float* __restrict__ X,
    const u16* __restrict__ Whi, const u16* __restrict__ Wlo,
    const float* __restrict__ bias,
    float* __restrict__ out_w, float* __restrict__ out_i)
{
    __shared__ __align__(16) char smem[65536];
    u16* Ahi = (u16*)smem;            // [128][KP]   10240 B
    u16* Alo = Ahi + BM * KP;         // [128][KP]   10240 B
    u16* Bhi = Alo + BM * KP;         // [256][KP]   20480 B
    u16* Blo = Bhi + N_EXPERTS * KP;  // [256][KP]   20480 B  (total 61440)
    float* Sc = (float*)smem;         // epilogue alias: [64][256] fp32 = 65536 B

    const int tid = threadIdx.x;
    const int m0 = blockIdx.x * BM;

    // --- staging assignment ---
    const int ar = tid >> 3;          // X row 0..63 (and +64)
    const int ac = (tid & 7) * 4;     // k offset (floats), 8 lanes cover 32 k
    const int br = tid >> 2;          // W row 0..127 (and +128)
    const int bc = (tid & 3) * 8;     // k offset (fp16), 4 lanes cover 32 k

    const float* xa = X + (size_t)(m0 + ar) * DIM + ac;
    const float* xb = X + (size_t)(m0 + ar + 64) * DIM + ac;
    const u16* wh0 = Whi + br * DIM + bc;
    const u16* wh1 = Whi + (br + 128) * DIM + bc;
    const u16* wl0 = Wlo + br * DIM + bc;
    const u16* wl1 = Wlo + (br + 128) * DIM + bc;

    // --- wave / fragment assignment ---
    const int lane = tid & 63;
    const int wave = tid >> 6;
    const int wm = wave >> 2;         // 0..1: token half
    const int wn = wave & 3;          // 0..3: expert quarter
    const int l16 = lane & 15;
    const int quad = lane >> 4;

    f32x4 acc[4][4];
    #pragma unroll
    for (int i = 0; i < 4; i++)
        #pragma unroll
        for (int j = 0; j < 4; j++) acc[i][j] = (f32x4){0.f, 0.f, 0.f, 0.f};

    // prefetch tile 0 into registers
    float4 a0 = *(const float4*)(xa);
    float4 a1 = *(const float4*)(xb);
    uint4 h0 = *(const uint4*)(wh0);
    uint4 h1 = *(const uint4*)(wh1);
    uint4 l0 = *(const uint4*)(wl0);
    uint4 l1 = *(const uint4*)(wl1);

    for (int it = 0; it < KITERS; ++it) {
        __syncthreads();   // all waves done reading LDS of previous tile
        // --- split A (fp32 -> fp16 hi/lo) + store; store B planes ---
        {
            ushort4 h, l;
            _Float16 t;
            t = (_Float16)a0.x; h.x = f16_bits(t); l.x = f16_bits((_Float16)(a0.x - (float)t));
            t = (_Float16)a0.y; h.y = f16_bits(t); l.y = f16_bits((_Float16)(a0.y - (float)t));
            t = (_Float16)a0.z; h.z = f16_bits(t); l.z = f16_bits((_Float16)(a0.z - (float)t));
            t = (_Float16)a0.w; h.w = f16_bits(t); l.w = f16_bits((_Float16)(a0.w - (float)t));
            *(ushort4*)&Ahi[ar * KP + ac] = h;
            *(ushort4*)&Alo[ar * KP + ac] = l;
            t = (_Float16)a1.x; h.x = f16_bits(t); l.x = f16_bits((_Float16)(a1.x - (float)t));
            t = (_Float16)a1.y; h.y = f16_bits(t); l.y = f16_bits((_Float16)(a1.y - (float)t));
            t = (_Float16)a1.z; h.z = f16_bits(t); l.z = f16_bits((_Float16)(a1.z - (float)t));
            t = (_Float16)a1.w; h.w = f16_bits(t); l.w = f16_bits((_Float16)(a1.w - (float)t));
            *(ushort4*)&Ahi[(ar + 64) * KP + ac] = h;
            *(ushort4*)&Alo[(ar + 64) * KP + ac] = l;
        }
        *(uint4*)&Bhi[br * KP + bc] = h0;
        *(uint4*)&Bhi[(br + 128) * KP + bc] = h1;
        *(uint4*)&Blo[br * KP + bc] = l0;
        *(uint4*)&Blo[(br + 128) * KP + bc] = l1;
        __syncthreads();

        // --- prefetch next tile (hidden under ~2000-cyc MFMA section) ---
        if (it + 1 < KITERS) {
            const int ko = (it + 1) * BK;
            a0 = *(const float4*)(xa + ko);
            a1 = *(const float4*)(xb + ko);
            h0 = *(const uint4*)(wh0 + ko);
            h1 = *(const uint4*)(wh1 + ko);
            l0 = *(const uint4*)(wl0 + ko);
            l1 = *(const uint4*)(wl1 + ko);
        }

        // --- LDS -> fragments (ds_read_b128, 80B row stride: 2-way = free) ---
        f16x8 fah[4], fal[4], fbh[4], fbl[4];
        #pragma unroll
        for (int i = 0; i < 4; i++) {
            const int mrow = wm * 64 + i * 16 + l16;
            fah[i] = *(const f16x8*)&Ahi[mrow * KP + quad * 8];
            fal[i] = *(const f16x8*)&Alo[mrow * KP + quad * 8];
            const int nrow = wn * 64 + i * 16 + l16;
            fbh[i] = *(const f16x8*)&Bhi[nrow * KP + quad * 8];
            fbl[i] = *(const f16x8*)&Blo[nrow * KP + quad * 8];
        }
        // --- 3-term split-fp16 MFMA: hh + hl + lh (ll term is O(2^-24)) ---
        #pragma unroll
        for (int i = 0; i < 4; i++)
            #pragma unroll
            for (int j = 0; j < 4; j++) {
                acc[i][j] = __builtin_amdgcn_mfma_f32_16x16x32_f16(fah[i], fbh[j], acc[i][j], 0, 0, 0);
                acc[i][j] = __builtin_amdgcn_mfma_f32_16x16x32_f16(fah[i], fbl[j], acc[i][j], 0, 0, 0);
                acc[i][j] = __builtin_amdgcn_mfma_f32_16x16x32_f16(fal[i], fbh[j], acc[i][j], 0, 0, 0);
            }
    }

    // --- epilogue: biased sigmoid scores -> LDS, then fused routing ---
    float bv[4];
    #pragma unroll
    for (int j = 0; j < 4; j++) bv[j] = bias[wn * 64 + j * 16 + l16];

    for (int pass = 0; pass < 2; ++pass) {
        __syncthreads();   // staging reads (p0) / prev routing (p1) complete
        if (wm == pass) {  // wave-uniform: 4 waves own these 64 token rows
            #pragma unroll
            for (int i = 0; i < 4; i++)
                #pragma unroll
                for (int j = 0; j < 4; j++)
                    #pragma unroll
                    for (int r = 0; r < 4; r++) {
                        const int trow = i * 16 + quad * 4 + r;          // 0..63
                        const int e = wn * 64 + j * 16 + l16;            // 0..255
                        const float logit = acc[i][j][r] * INV_W_SCALE;
                        const float s = 1.f / (1.f + expf(-logit));
                        Sc[trow * N_EXPERTS + e] = s + bv[j];            // BIASED
                    }
        }
        __syncthreads();

        if (tid < 64) {    // one wave routes 64 tokens; lane-staggered LDS reads
            const float* row = Sc + tid * N_EXPERTS;

            // group score = sum of top-2 biased (matches jax order: m1+m2)
            float gs[N_GROUPS];
            #pragma unroll
            for (int g = 0; g < N_GROUPS; g++) {
                float m1 = -INFINITY, m2 = -INFINITY;
                for (int jj = 0; jj < EPG; jj++) {
                    const float v = row[g * EPG + ((tid + jj) & (EPG - 1))];
                    if (v > m1) { m2 = m1; m1 = v; }
                    else if (v > m2) { m2 = v; }
                }
                gs[g] = m1 + m2;
            }
            // keep top-4 groups (jax tie-break: lower index wins)
            unsigned keep = 0;
            #pragma unroll
            for (int g = 0; g < N_GROUPS; g++) {
                int cnt = 0;
                #pragma unroll
                for (int h = 0; h < N_GROUPS; h++)
                    if (gs[h] > gs[g] || (gs[h] == gs[g] && h < g)) cnt++;
                if (cnt < TOPK_GROUPS) keep |= (1u << g);
            }
            // top-8 experts within kept groups; comparator (v desc, idx asc)
            // makes result independent of staggered scan order
            float tv[TOPK]; int ti[TOPK];
            #pragma unroll
            for (int i = 0; i < TOPK; i++) { tv[i] = -INFINITY; ti[i] = 0x7fffffff; }
            for (int g = 0; g < N_GROUPS; g++) {
                if (!(keep & (1u << g))) continue;
                for (int jj = 0; jj < EPG; jj++) {
                    const int e = g * EPG + ((tid + jj) & (EPG - 1));
                    const float v = row[e];
                    if (v > tv[TOPK - 1] || (v == tv[TOPK - 1] && e < ti[TOPK - 1])) {
                        float cv = v; int ce = e;
                        #pragma unroll
                        for (int s = 0; s < TOPK; s++) {
                            const bool b = (cv > tv[s]) || (cv == tv[s] && ce < ti[s]);
                            if (b) {
                                const float t1 = tv[s]; tv[s] = cv; cv = t1;
                                const int t2 = ti[s]; ti[s] = ce; ce = t2;
                            }
                        }
                    }
                }
            }
            // weights from RAW scores (biased - bias), normalize, scale
            float w[TOPK], sum = 0.f;
            #pragma unroll
            for (int i = 0; i < TOPK; i++) {
                w[i] = row[ti[i]] - bias[ti[i]];
                sum += w[i];
            }
            const float scale = ROUTE_SCALE / fmaxf(sum, 1e-10f);
            const size_t t = (size_t)m0 + pass * 64 + tid;
            #pragma unroll
            for (int i = 0; i < TOPK; i++) {
                out_w[t * TOPK + i] = w[i] * scale;
                out_i[t * TOPK + i] = (float)ti[i];
            }
        }
    }
}

extern "C" void kernel_launch(void* const* d_in, const int* in_sizes, int n_in,
                              void* d_out, int out_size, void* d_ws, size_t ws_size,
                              hipStream_t stream)
{
    const float* x = (const float*)d_in[0];     // (T, D)
    const float* w = (const float*)d_in[1];     // (E, D)
    const float* b = (const float*)d_in[2];     // (E,)

    u16* whi = (u16*)d_ws;                      // (E, D) fp16 hi plane, 1 MB
    u16* wlo = whi + (size_t)N_EXPERTS * DIM;   // (E, D) fp16 lo plane, 1 MB

    float* out_w = (float*)d_out;                              // (T, 8)
    float* out_i = (float*)d_out + (size_t)T_TOKENS * TOPK;    // (T, 8) as fp32

    convert_w<<<(N_EXPERTS * DIM) / 256, 256, 0, stream>>>(w, whi, wlo);
    fused_gate<<<T_TOKENS / BM, 512, 0, stream>>>(x, whi, wlo, b, out_w, out_i);
}